// Round 1
// baseline (7633.405 us; speedup 1.0000x reference)
//
#include <hip/hip_runtime.h>
#include <cstddef>

// K-Planes field eval: 4 scales x 3 planes bilinear sample (32ch), 3-way
// product per scale -> 128 feats -> MLP 128->64->64->1 (ReLU, bias-free).
//
// Strategy R1:
//  - transpose grids [C,H,W] -> [H,W,C] into d_ws (coalesced 128B corner reads)
//  - fused sample+MLP kernel, thread-per-point, f32 throughout
//  - weights read at wave-uniform addresses -> compiler emits s_load + v_fmac

struct KParams {
  const float* x;
  const float* g[12];
  const float* w0;
  const float* w1;
  const float* w2;
  float* out;
  int N;
};

__global__ __launch_bounds__(256) void transpose_chw_hwc(
    const float* __restrict__ in, float* __restrict__ out, int RR) {
  // in: [32][RR]  ->  out: [RR][32]
  __shared__ float tile[32][65];  // +1 pad: conflict-free both phases
  const int p0 = blockIdx.x * 64;
  {
    const int tp = threadIdx.x & 63;   // position in tile
    const int tc = threadIdx.x >> 6;   // 0..3
#pragma unroll
    for (int cc = 0; cc < 8; ++cc) {
      const int c = cc * 4 + tc;
      tile[c][tp] = in[(size_t)c * RR + p0 + tp];  // coalesced 64-wide
    }
  }
  __syncthreads();
  {
    const int c = threadIdx.x & 31;    // channel
    const int tq = threadIdx.x >> 5;   // 0..7
#pragma unroll
    for (int pp = 0; pp < 8; ++pp) {
      const int pos = pp * 8 + tq;
      out[(size_t)(p0 + pos) * 32 + c] = tile[c][pos];  // fully coalesced
    }
  }
}

__device__ __forceinline__ float4 ld4(const float* p) {
  return *reinterpret_cast<const float4*>(p);
}

__device__ __forceinline__ float4 bilerp4(float4 a, float4 b, float4 c, float4 d,
                                          float wx, float wy) {
  float4 r;
  float t0, t1;
  t0 = a.x + wx * (b.x - a.x); t1 = c.x + wx * (d.x - c.x); r.x = t0 + wy * (t1 - t0);
  t0 = a.y + wx * (b.y - a.y); t1 = c.y + wx * (d.y - c.y); r.y = t0 + wy * (t1 - t0);
  t0 = a.z + wx * (b.z - a.z); t1 = c.z + wx * (d.z - c.z); r.z = t0 + wy * (t1 - t0);
  t0 = a.w + wx * (b.w - a.w); t1 = c.w + wx * (d.w - c.w); r.w = t0 + wy * (t1 - t0);
  return r;
}

template <bool CHLAST>
__global__ __launch_bounds__(256) void kplanes_fused(KParams P) {
  const int i = blockIdx.x * 256 + threadIdx.x;
  if (i >= P.N) return;
  const float c0 = P.x[3 * i + 0];
  const float c1 = P.x[3 * i + 1];
  const float c2 = P.x[3 * i + 2];

  float h0[64];
#pragma unroll
  for (int j = 0; j < 64; ++j) h0[j] = 0.0f;

#pragma unroll
  for (int s = 0; s < 4; ++s) {
    const int R = 128 << s;
    const int RR = R * R;
    float feat[32];
#pragma unroll
    for (int c = 0; c < 32; ++c) feat[c] = 1.0f;

#pragma unroll
    for (int pl = 0; pl < 3; ++pl) {
      // PLANES = (0,1),(0,2),(1,2); cx -> W axis, cy -> H axis
      const float cx = (pl == 2) ? c1 : c0;
      const float cy = (pl == 0) ? c1 : c2;
      const float Rm1 = (float)(R - 1);
      const float u = fminf(fmaxf((cx + 1.0f) * 0.5f * Rm1, 0.0f), Rm1);
      const float v = fminf(fmaxf((cy + 1.0f) * 0.5f * Rm1, 0.0f), Rm1);
      const float fx0 = floorf(u), fy0 = floorf(v);
      const float wx = u - fx0, wy = v - fy0;
      const int x0 = (int)fx0, y0 = (int)fy0;
      const int x1 = min(x0 + 1, R - 1), y1 = min(y0 + 1, R - 1);
      const float* gp = P.g[s * 3 + pl];

      if (CHLAST) {
        // [H,W,C]: 32 channels contiguous per corner (128 B)
        const float* b00 = gp + (size_t)(y0 * R + x0) * 32;
        const float* b01 = gp + (size_t)(y0 * R + x1) * 32;
        const float* b10 = gp + (size_t)(y1 * R + x0) * 32;
        const float* b11 = gp + (size_t)(y1 * R + x1) * 32;
#pragma unroll
        for (int c4 = 0; c4 < 8; ++c4) {
          const float4 a = ld4(b00 + c4 * 4);
          const float4 b = ld4(b01 + c4 * 4);
          const float4 c = ld4(b10 + c4 * 4);
          const float4 d = ld4(b11 + c4 * 4);
          const float4 r = bilerp4(a, b, c, d, wx, wy);
          feat[c4 * 4 + 0] *= r.x;
          feat[c4 * 4 + 1] *= r.y;
          feat[c4 * 4 + 2] *= r.z;
          feat[c4 * 4 + 3] *= r.w;
        }
      } else {
        // fallback: original [C,H,W] layout (slow path, correctness only)
        const int i00 = y0 * R + x0, i01 = y0 * R + x1;
        const int i10 = y1 * R + x0, i11 = y1 * R + x1;
#pragma unroll 8
        for (int c = 0; c < 32; ++c) {
          const float a = gp[(size_t)c * RR + i00];
          const float b = gp[(size_t)c * RR + i01];
          const float cc = gp[(size_t)c * RR + i10];
          const float d = gp[(size_t)c * RR + i11];
          const float t0 = a + wx * (b - a);
          const float t1 = cc + wx * (d - cc);
          feat[c] *= t0 + wy * (t1 - t0);
        }
      }
    }

    // accumulate this scale's 32 features into h0 (w0 rows: wave-uniform -> s_load)
    const float* w0s = P.w0 + (size_t)s * 32 * 64;
#pragma unroll
    for (int k = 0; k < 32; ++k) {
      const float fk = feat[k];
#pragma unroll
      for (int j = 0; j < 64; ++j)
        h0[j] = fmaf(fk, w0s[k * 64 + j], h0[j]);
    }
  }

  // layer 1: h1 = relu(h0) @ w1
  float h1[64];
#pragma unroll
  for (int j = 0; j < 64; ++j) h1[j] = 0.0f;
#pragma unroll
  for (int k = 0; k < 64; ++k) {
    const float a = fmaxf(h0[k], 0.0f);
#pragma unroll
    for (int j = 0; j < 64; ++j)
      h1[j] = fmaf(a, P.w1[k * 64 + j], h1[j]);
  }

  // output: relu(h1) @ w2
  float o = 0.0f;
#pragma unroll
  for (int j = 0; j < 64; ++j)
    o = fmaf(fmaxf(h1[j], 0.0f), P.w2[j], o);
  P.out[i] = o;
}

extern "C" void kernel_launch(void* const* d_in, const int* in_sizes, int n_in,
                              void* d_out, int out_size, void* d_ws, size_t ws_size,
                              hipStream_t stream) {
  KParams P;
  P.x = (const float*)d_in[0];
  P.w0 = (const float*)d_in[13];
  P.w1 = (const float*)d_in[14];
  P.w2 = (const float*)d_in[15];
  P.out = (float*)d_out;
  const int N = in_sizes[0] / 3;
  P.N = N;

  size_t need = 0;
  for (int s = 0; s < 4; ++s) {
    const size_t R = (size_t)(128 << s);
    need += 3ull * 32ull * R * R * sizeof(float);
  }

  if (ws_size >= need) {
    float* w = (float*)d_ws;
    size_t off = 0;
    for (int s = 0; s < 4; ++s) {
      const int R = 128 << s;
      const int RR = R * R;
      for (int pl = 0; pl < 3; ++pl) {
        const float* src = (const float*)d_in[1 + s * 3 + pl];
        transpose_chw_hwc<<<RR / 64, 256, 0, stream>>>(src, w + off, RR);
        P.g[s * 3 + pl] = w + off;
        off += (size_t)32 * RR;
      }
    }
    kplanes_fused<true><<<(N + 255) / 256, 256, 0, stream>>>(P);
  } else {
    for (int k = 0; k < 12; ++k) P.g[k] = (const float*)d_in[1 + k];
    kplanes_fused<false><<<(N + 255) / 256, 256, 0, stream>>>(P);
  }
}

// Round 2
// 1718.766 us; speedup vs baseline: 4.4412x; 4.4412x over previous
//
#include <hip/hip_runtime.h>
#include <cstddef>

// K-Planes field eval: 4 scales x 3 planes bilinear sample (32ch), 3-way
// product per scale -> 128 feats -> MLP 128->64->64->1 (ReLU, bias-free).
//
// R2 strategy:
//  - transpose grids [C,H,W] -> [H,W,C] into d_ws (coalesced 128B corner reads)
//  - fused kernel: 256 threads = 64 points.
//      gather: 4 threads/point, 8 channels each -> feat[4][8] (32 regs)
//      MLP: feats via LDS; thread (g=t>>6, p=t&63) computes 16-wide j-chunk;
//           g forced wave-uniform (readfirstlane) -> all weights via s_load.
//  - no 64-wide per-thread arrays -> no spills, VGPR<=128, 4 waves/SIMD.

struct KParams {
  const float* x;
  const float* g[12];
  const float* w0;
  const float* w1;
  const float* w2;
  float* out;
  int N;
};

__global__ __launch_bounds__(256) void transpose_chw_hwc(
    const float* __restrict__ in, float* __restrict__ out, int RR) {
  // in: [32][RR]  ->  out: [RR][32]
  __shared__ float tile[32][65];
  const int p0 = blockIdx.x * 64;
  {
    const int tp = threadIdx.x & 63;
    const int tc = threadIdx.x >> 6;
#pragma unroll
    for (int cc = 0; cc < 8; ++cc) {
      const int c = cc * 4 + tc;
      tile[c][tp] = in[(size_t)c * RR + p0 + tp];
    }
  }
  __syncthreads();
  {
    const int c = threadIdx.x & 31;
    const int tq = threadIdx.x >> 5;
#pragma unroll
    for (int pp = 0; pp < 8; ++pp) {
      const int pos = pp * 8 + tq;
      out[(size_t)(p0 + pos) * 32 + c] = tile[c][pos];
    }
  }
}

__device__ __forceinline__ float4 ld4(const float* p) {
  return *reinterpret_cast<const float4*>(p);
}

template <bool CHLAST>
__global__ __launch_bounds__(256, 4) void kplanes_fused(KParams P) {
  __shared__ float fl[64][129];  // feats; reused for relu(h0); then o-parts

  const int t = threadIdx.x;
  const int pg = t >> 2;   // gather-phase local point 0..63
  const int sub = t & 3;   // channel group: channels [sub*8, sub*8+8)
  const int blk0 = blockIdx.x * 64;

  // ---------------- gather: feat[s][c] for channels sub*8+c ----------------
  int Pi = blk0 + pg;
  if (Pi >= P.N) Pi = P.N - 1;
  const float c0 = P.x[3 * Pi + 0];
  const float c1 = P.x[3 * Pi + 1];
  const float c2 = P.x[3 * Pi + 2];

  float feat[4][8];
#pragma unroll
  for (int s = 0; s < 4; ++s)
#pragma unroll
    for (int c = 0; c < 8; ++c) feat[s][c] = 1.0f;

#pragma unroll
  for (int s = 0; s < 4; ++s) {
    const int R = 128 << s;
    const int RR = R * R;
#pragma unroll
    for (int pl = 0; pl < 3; ++pl) {
      // PLANES = (0,1),(0,2),(1,2); cx -> W axis, cy -> H axis
      const float cx = (pl == 2) ? c1 : c0;
      const float cy = (pl == 0) ? c1 : c2;
      const float Rm1 = (float)(R - 1);
      const float u = fminf(fmaxf((cx + 1.0f) * 0.5f * Rm1, 0.0f), Rm1);
      const float v = fminf(fmaxf((cy + 1.0f) * 0.5f * Rm1, 0.0f), Rm1);
      const float fx0 = floorf(u), fy0 = floorf(v);
      const float wx = u - fx0, wy = v - fy0;
      const int x0 = (int)fx0, y0 = (int)fy0;
      const int x1 = min(x0 + 1, R - 1), y1 = min(y0 + 1, R - 1);
      const float* gp = P.g[s * 3 + pl];

      if (CHLAST) {
        const float* b00 = gp + (size_t)(y0 * R + x0) * 32 + sub * 8;
        const float* b01 = gp + (size_t)(y0 * R + x1) * 32 + sub * 8;
        const float* b10 = gp + (size_t)(y1 * R + x0) * 32 + sub * 8;
        const float* b11 = gp + (size_t)(y1 * R + x1) * 32 + sub * 8;
#pragma unroll
        for (int h = 0; h < 2; ++h) {
          const float4 a = ld4(b00 + h * 4);
          const float4 b = ld4(b01 + h * 4);
          const float4 cc = ld4(b10 + h * 4);
          const float4 d = ld4(b11 + h * 4);
          float t0, t1;
          t0 = a.x + wx * (b.x - a.x); t1 = cc.x + wx * (d.x - cc.x);
          feat[s][h * 4 + 0] *= t0 + wy * (t1 - t0);
          t0 = a.y + wx * (b.y - a.y); t1 = cc.y + wx * (d.y - cc.y);
          feat[s][h * 4 + 1] *= t0 + wy * (t1 - t0);
          t0 = a.z + wx * (b.z - a.z); t1 = cc.z + wx * (d.z - cc.z);
          feat[s][h * 4 + 2] *= t0 + wy * (t1 - t0);
          t0 = a.w + wx * (b.w - a.w); t1 = cc.w + wx * (d.w - cc.w);
          feat[s][h * 4 + 3] *= t0 + wy * (t1 - t0);
        }
      } else {
        const int i00 = y0 * R + x0, i01 = y0 * R + x1;
        const int i10 = y1 * R + x0, i11 = y1 * R + x1;
#pragma unroll
        for (int c = 0; c < 8; ++c) {
          const size_t cb = (size_t)(sub * 8 + c) * RR;
          const float a = gp[cb + i00];
          const float b = gp[cb + i01];
          const float cc = gp[cb + i10];
          const float d = gp[cb + i11];
          const float t0 = a + wx * (b - a);
          const float t1 = cc + wx * (d - cc);
          feat[s][c] *= t0 + wy * (t1 - t0);
        }
      }
    }
  }

  // publish feats: fl[p][s*32 + sub*8 + c]  (stride 129 -> 2-way banks, free)
#pragma unroll
  for (int s = 0; s < 4; ++s)
#pragma unroll
    for (int c = 0; c < 8; ++c)
      fl[pg][s * 32 + sub * 8 + c] = feat[s][c];
  __syncthreads();

  // ---------------- MLP: thread (g,p) does j in [g*16, g*16+16) -----------
  const int p = t & 63;
  const int g = __builtin_amdgcn_readfirstlane(t >> 6);  // wave-uniform

  // layer 0: h0[g*16+jj] = sum_k feat[k] * w0[k][g*16+jj]
  const float* w0c = P.w0 + g * 16;  // w0[k][j] = P.w0[k*64 + j]
  float part[16];
#pragma unroll
  for (int jj = 0; jj < 16; ++jj) part[jj] = 0.0f;
#pragma unroll 16
  for (int k = 0; k < 128; ++k) {
    const float f = fl[p][k];
#pragma unroll
    for (int jj = 0; jj < 16; ++jj)
      part[jj] = fmaf(f, w0c[(size_t)k * 64 + jj], part[jj]);
  }

  __syncthreads();  // everyone done reading feats
#pragma unroll
  for (int jj = 0; jj < 16; ++jj)
    fl[p][g * 16 + jj] = fmaxf(part[jj], 0.0f);  // relu(h0) into cols 0..63
  __syncthreads();

  // layer 1: h1[g*16+jj] = sum_k relu(h0)[k] * w1[k][g*16+jj]
  const float* w1c = P.w1 + g * 16;
  float h1[16];
#pragma unroll
  for (int jj = 0; jj < 16; ++jj) h1[jj] = 0.0f;
#pragma unroll 16
  for (int k = 0; k < 64; ++k) {
    const float a = fl[p][k];
#pragma unroll
    for (int jj = 0; jj < 16; ++jj)
      h1[jj] = fmaf(a, w1c[(size_t)k * 64 + jj], h1[jj]);
  }

  // output partial: sum_jj relu(h1[jj]) * w2[g*16+jj]
  const float* w2c = P.w2 + g * 16;
  float o = 0.0f;
#pragma unroll
  for (int jj = 0; jj < 16; ++jj)
    o = fmaf(fmaxf(h1[jj], 0.0f), w2c[jj], o);

  __syncthreads();  // done reading relu(h0) from fl
  ((float*)fl)[g * 64 + p] = o;
  __syncthreads();

  if (t < 64) {
    const int Po = blk0 + t;
    if (Po < P.N) {
      const float* f0 = (const float*)fl;
      P.out[Po] = (f0[t] + f0[64 + t]) + (f0[128 + t] + f0[192 + t]);
    }
  }
}

extern "C" void kernel_launch(void* const* d_in, const int* in_sizes, int n_in,
                              void* d_out, int out_size, void* d_ws, size_t ws_size,
                              hipStream_t stream) {
  KParams P;
  P.x = (const float*)d_in[0];
  P.w0 = (const float*)d_in[13];
  P.w1 = (const float*)d_in[14];
  P.w2 = (const float*)d_in[15];
  P.out = (float*)d_out;
  const int N = in_sizes[0] / 3;
  P.N = N;

  size_t need = 0;
  for (int s = 0; s < 4; ++s) {
    const size_t R = (size_t)(128 << s);
    need += 3ull * 32ull * R * R * sizeof(float);
  }

  const int nblk = (N + 63) / 64;
  if (ws_size >= need) {
    float* w = (float*)d_ws;
    size_t off = 0;
    for (int s = 0; s < 4; ++s) {
      const int R = 128 << s;
      const int RR = R * R;
      for (int pl = 0; pl < 3; ++pl) {
        const float* src = (const float*)d_in[1 + s * 3 + pl];
        transpose_chw_hwc<<<RR / 64, 256, 0, stream>>>(src, w + off, RR);
        P.g[s * 3 + pl] = w + off;
        off += (size_t)32 * RR;
      }
    }
    kplanes_fused<true><<<nblk, 256, 0, stream>>>(P);
  } else {
    for (int k = 0; k < 12; ++k) P.g[k] = (const float*)d_in[1 + k];
    kplanes_fused<false><<<nblk, 256, 0, stream>>>(P);
  }
}

// Round 3
// 854.899 us; speedup vs baseline: 8.9290x; 2.0105x over previous
//
#include <hip/hip_runtime.h>
#include <cstddef>

// K-Planes field eval: 4 scales x 3 planes bilinear sample (32ch), 3-way
// product per scale -> 128 feats -> MLP 128->64->64->1 (ReLU, bias-free).
//
// R3 strategy:
//  - transpose+convert grids [C,H,W] f32 -> [H,W,C] bf16 into d_ws
//      (halves gather traffic; 267 MB working set ~ fits 256 MB L3)
//  - fused kernel: 512 threads = 64 points, LDS 33KB -> 4 blk/CU -> 32 waves/CU
//      gather: 8 threads/point, 4 channels each -> feat[4][4] (16 regs)
//      MLP: feats via LDS; thread (g=t>>6, p=t&63) computes 8-wide j-chunk;
//           g wave-uniform (readfirstlane) -> all weights via s_load.
//  - __launch_bounds__(512,8) caps VGPR at 64 for full occupancy.

typedef unsigned short ushort_t;
typedef unsigned int uint_t;

struct KParams {
  const float* x;
  const void* g[12];
  const float* w0;
  const float* w1;
  const float* w2;
  float* out;
  int N;
};

__device__ __forceinline__ ushort_t f32_to_bf16_rne(float f) {
  uint_t u = __float_as_uint(f);
  u = (u + 0x7FFFu + ((u >> 16) & 1u)) >> 16;
  return (ushort_t)u;
}
__device__ __forceinline__ float bf16_to_f32(ushort_t h) {
  return __uint_as_float(((uint_t)h) << 16);
}

// in: [32][RR] f32  ->  out: [RR][32] bf16
__global__ __launch_bounds__(256) void transpose_chw_hwc_bf16(
    const float* __restrict__ in, ushort_t* __restrict__ out, int RR) {
  __shared__ float tile[32][65];
  const int p0 = blockIdx.x * 64;
  {
    const int tp = threadIdx.x & 63;
    const int tc = threadIdx.x >> 6;
#pragma unroll
    for (int cc = 0; cc < 8; ++cc) {
      const int c = cc * 4 + tc;
      tile[c][tp] = in[(size_t)c * RR + p0 + tp];
    }
  }
  __syncthreads();
  {
    const int c2 = threadIdx.x & 15;   // channel pair
    const int tq = threadIdx.x >> 4;   // 0..15
    uint_t* o32 = (uint_t*)out;
#pragma unroll
    for (int pp = 0; pp < 4; ++pp) {
      const int pos = pp * 16 + tq;
      const uint_t lo = f32_to_bf16_rne(tile[2 * c2 + 0][pos]);
      const uint_t hi = f32_to_bf16_rne(tile[2 * c2 + 1][pos]);
      o32[(size_t)(p0 + pos) * 16 + c2] = lo | (hi << 16);
    }
  }
}

template <bool CHLAST>
__global__ __launch_bounds__(512, 8) void kplanes_fused(KParams P) {
  __shared__ float fl[64][129];  // feats; then relu(h0); then o-parts

  const int t = threadIdx.x;
  const int pg = t >> 3;   // gather-phase local point 0..63
  const int sub = t & 7;   // channel group: channels [sub*4, sub*4+4)
  const int blk0 = blockIdx.x * 64;

  // ---------------- gather: feat[s][c] for channels sub*4+c ----------------
  int Pi = blk0 + pg;
  if (Pi >= P.N) Pi = P.N - 1;
  const float c0 = P.x[3 * Pi + 0];
  const float c1 = P.x[3 * Pi + 1];
  const float c2 = P.x[3 * Pi + 2];

  float feat[4][4];
#pragma unroll
  for (int s = 0; s < 4; ++s)
#pragma unroll
    for (int c = 0; c < 4; ++c) feat[s][c] = 1.0f;

#pragma unroll
  for (int s = 0; s < 4; ++s) {
    const int R = 128 << s;
    const int RR = R * R;
#pragma unroll
    for (int pl = 0; pl < 3; ++pl) {
      // PLANES = (0,1),(0,2),(1,2); cx -> W axis, cy -> H axis
      const float cx = (pl == 2) ? c1 : c0;
      const float cy = (pl == 0) ? c1 : c2;
      const float Rm1 = (float)(R - 1);
      const float u = fminf(fmaxf((cx + 1.0f) * 0.5f * Rm1, 0.0f), Rm1);
      const float v = fminf(fmaxf((cy + 1.0f) * 0.5f * Rm1, 0.0f), Rm1);
      const float fx0 = floorf(u), fy0 = floorf(v);
      const float wx = u - fx0, wy = v - fy0;
      const int x0 = (int)fx0, y0 = (int)fy0;
      const int x1 = min(x0 + 1, R - 1), y1 = min(y0 + 1, R - 1);
      // corner weights: 1 mul + 3 fma per channel
      const float w11 = wx * wy;
      const float w10 = wy - w11;        // (1-wx)*wy
      const float w01 = wx - w11;        // wx*(1-wy)
      const float w00 = 1.0f - wx - w10; // (1-wx)*(1-wy)

      if (CHLAST) {
        const ushort_t* gp = (const ushort_t*)P.g[s * 3 + pl];
        const ushort_t* b00 = gp + (size_t)(y0 * R + x0) * 32 + sub * 4;
        const ushort_t* b01 = gp + (size_t)(y0 * R + x1) * 32 + sub * 4;
        const ushort_t* b10 = gp + (size_t)(y1 * R + x0) * 32 + sub * 4;
        const ushort_t* b11 = gp + (size_t)(y1 * R + x1) * 32 + sub * 4;
        const ushort4 a = *reinterpret_cast<const ushort4*>(b00);
        const ushort4 b = *reinterpret_cast<const ushort4*>(b01);
        const ushort4 cc = *reinterpret_cast<const ushort4*>(b10);
        const ushort4 d = *reinterpret_cast<const ushort4*>(b11);
        feat[s][0] *= bf16_to_f32(a.x) * w00 + bf16_to_f32(b.x) * w01 +
                      bf16_to_f32(cc.x) * w10 + bf16_to_f32(d.x) * w11;
        feat[s][1] *= bf16_to_f32(a.y) * w00 + bf16_to_f32(b.y) * w01 +
                      bf16_to_f32(cc.y) * w10 + bf16_to_f32(d.y) * w11;
        feat[s][2] *= bf16_to_f32(a.z) * w00 + bf16_to_f32(b.z) * w01 +
                      bf16_to_f32(cc.z) * w10 + bf16_to_f32(d.z) * w11;
        feat[s][3] *= bf16_to_f32(a.w) * w00 + bf16_to_f32(b.w) * w01 +
                      bf16_to_f32(cc.w) * w10 + bf16_to_f32(d.w) * w11;
      } else {
        const float* gp = (const float*)P.g[s * 3 + pl];
        const int i00 = y0 * R + x0, i01 = y0 * R + x1;
        const int i10 = y1 * R + x0, i11 = y1 * R + x1;
#pragma unroll
        for (int c = 0; c < 4; ++c) {
          const size_t cb = (size_t)(sub * 4 + c) * RR;
          feat[s][c] *= gp[cb + i00] * w00 + gp[cb + i01] * w01 +
                        gp[cb + i10] * w10 + gp[cb + i11] * w11;
        }
      }
    }
  }

  // publish feats: fl[p][s*32 + sub*4 + c]  (stride 129 -> benign banks)
#pragma unroll
  for (int s = 0; s < 4; ++s)
#pragma unroll
    for (int c = 0; c < 4; ++c)
      fl[pg][s * 32 + sub * 4 + c] = feat[s][c];
  __syncthreads();

  // ---------------- MLP: thread (g,p) does j in [g*8, g*8+8) --------------
  const int p = t & 63;
  const int g = __builtin_amdgcn_readfirstlane(t >> 6);  // wave-uniform 0..7

  // layer 0: h0[g*8+jj] = sum_k feat[k] * w0[k][g*8+jj]
  const float* w0c = P.w0 + g * 8;
  float part[8];
#pragma unroll
  for (int jj = 0; jj < 8; ++jj) part[jj] = 0.0f;
#pragma unroll 16
  for (int k = 0; k < 128; ++k) {
    const float f = fl[p][k];
#pragma unroll
    for (int jj = 0; jj < 8; ++jj)
      part[jj] = fmaf(f, w0c[(size_t)k * 64 + jj], part[jj]);
  }

  __syncthreads();  // everyone done reading feats
#pragma unroll
  for (int jj = 0; jj < 8; ++jj)
    fl[p][g * 8 + jj] = fmaxf(part[jj], 0.0f);  // relu(h0) into cols 0..63
  __syncthreads();

  // layer 1: h1[g*8+jj] = sum_k relu(h0)[k] * w1[k][g*8+jj]
  const float* w1c = P.w1 + g * 8;
  float h1[8];
#pragma unroll
  for (int jj = 0; jj < 8; ++jj) h1[jj] = 0.0f;
#pragma unroll 16
  for (int k = 0; k < 64; ++k) {
    const float a = fl[p][k];
#pragma unroll
    for (int jj = 0; jj < 8; ++jj)
      h1[jj] = fmaf(a, w1c[(size_t)k * 64 + jj], h1[jj]);
  }

  // output partial: sum_jj relu(h1[jj]) * w2[g*8+jj]
  const float* w2c = P.w2 + g * 8;
  float o = 0.0f;
#pragma unroll
  for (int jj = 0; jj < 8; ++jj)
    o = fmaf(fmaxf(h1[jj], 0.0f), w2c[jj], o);

  __syncthreads();  // done reading relu(h0) from fl
  ((float*)fl)[g * 64 + p] = o;
  __syncthreads();

  if (t < 64) {
    const int Po = blk0 + t;
    if (Po < P.N) {
      const float* f0 = (const float*)fl;
      float r = 0.0f;
#pragma unroll
      for (int j = 0; j < 8; ++j) r += f0[j * 64 + t];
      P.out[Po] = r;
    }
  }
}

extern "C" void kernel_launch(void* const* d_in, const int* in_sizes, int n_in,
                              void* d_out, int out_size, void* d_ws, size_t ws_size,
                              hipStream_t stream) {
  KParams P;
  P.x = (const float*)d_in[0];
  P.w0 = (const float*)d_in[13];
  P.w1 = (const float*)d_in[14];
  P.w2 = (const float*)d_in[15];
  P.out = (float*)d_out;
  const int N = in_sizes[0] / 3;
  P.N = N;

  size_t need = 0;
  for (int s = 0; s < 4; ++s) {
    const size_t R = (size_t)(128 << s);
    need += 3ull * 32ull * R * R * sizeof(ushort_t);
  }

  const int nblk = (N + 63) / 64;
  if (ws_size >= need) {
    ushort_t* w = (ushort_t*)d_ws;
    size_t off = 0;
    for (int s = 0; s < 4; ++s) {
      const int R = 128 << s;
      const int RR = R * R;
      for (int pl = 0; pl < 3; ++pl) {
        const float* src = (const float*)d_in[1 + s * 3 + pl];
        transpose_chw_hwc_bf16<<<RR / 64, 256, 0, stream>>>(src, w + off, RR);
        P.g[s * 3 + pl] = w + off;
        off += (size_t)32 * RR;
      }
    }
    kplanes_fused<true><<<nblk, 512, 0, stream>>>(P);
  } else {
    for (int k = 0; k < 12; ++k) P.g[k] = (const void*)d_in[1 + k];
    kplanes_fused<false><<<nblk, 512, 0, stream>>>(P);
  }
}